// Round 4
// baseline (567.843 us; speedup 1.0000x reference)
//
#include <hip/hip_runtime.h>
#include <stdint.h>

// Problem constants: L=128, N=8, S=16384, C=B=V=256
#define L_Q 128
#define N_B 8
#define S_P 16384

typedef _Float16 half8 __attribute__((ext_vector_type(8)));
typedef float f32x4 __attribute__((ext_vector_type(4)));

// Workspace layout (float offsets) — total 526336 floats = 2,105,344 bytes:
//   WpT   fp32 [C][B]      65536 @ 0        (k_final, coalesced [c][b])
//   WvT   fp32 [B][V]      65536 @ 65536
//   WoT   fp32 [V][C]      65536 @ 131072
//   Wp_hi f16  [B][C]      32768 @ 196608   (k_main GEMM1 B-operand)
//   Wp_lo f16  [B][C]      32768 @ 229376
//   q_hi  f16  [N][L][B]  131072 @ 262144   (k_main GEMM2 A-operand)
//   q_lo  f16  [N][L][B]  131072 @ 393216
//   packed u64 [N*L]        2048 @ 524288

// ---------------------------------------------------------------------------
// Merged prep (blocks 0..255) + q_proj (blocks 256..511).
__global__ __launch_bounds__(256) void k_prep_qproj(
    const float* __restrict__ Wp, const float* __restrict__ Wv,
    const float* __restrict__ Wo,
    float* __restrict__ WpT, float* __restrict__ WvT, float* __restrict__ WoT,
    _Float16* __restrict__ Wp_hi, _Float16* __restrict__ Wp_lo,
    unsigned long long* __restrict__ packed,
    const float* __restrict__ tgt, const float* __restrict__ qpos,
    const float* __restrict__ Wq, const float* __restrict__ bq,
    _Float16* __restrict__ q_hi, _Float16* __restrict__ q_lo) {
  __shared__ __align__(16) float q_lds[4][256];
  int tid = threadIdx.x;
  if (blockIdx.x < 256) {
    // ---- prep ----
    int idx = (blockIdx.x << 8) + tid;     // 0..65535
    int r = idx >> 8, c = idx & 255;
    int t = (c << 8) + r;
    float wp = Wp[idx];
    WpT[t] = wp;
    WvT[t] = Wv[idx];
    WoT[t] = Wo[idx];
    _Float16 h = (_Float16)wp;
    Wp_hi[idx] = h;                        // [b][c], no transpose
    Wp_lo[idx] = (_Float16)(wp - (float)h);
    if (idx < N_B * L_Q) packed[idx] = 0ull;  // any real logit packs to > 0
    return;
  }
  // ---- q_proj (fp32 VALU; Wq row per thread, per-thread contiguous) ----
  int r0 = (blockIdx.x - 256) << 2;
  #pragma unroll
  for (int j = 0; j < 4; ++j) {
    int p = (j << 8) + tid;
    int rl = p >> 8, c = p & 255;
    int g = ((r0 + rl) << 8) + c;          // (l*8+n) row-major
    q_lds[rl][c] = tgt[g] + qpos[g];
  }
  __syncthreads();
  float bqv = bq[tid];
  float a0 = bqv, a1 = bqv, a2 = bqv, a3 = bqv;
  #pragma unroll 4
  for (int c = 0; c < 256; c += 4) {
    float4 w = *(const float4*)(Wq + (tid << 8) + c);
    a0 = fmaf(w.x, q_lds[0][c], fmaf(w.y, q_lds[0][c+1],
         fmaf(w.z, q_lds[0][c+2], fmaf(w.w, q_lds[0][c+3], a0))));
    a1 = fmaf(w.x, q_lds[1][c], fmaf(w.y, q_lds[1][c+1],
         fmaf(w.z, q_lds[1][c+2], fmaf(w.w, q_lds[1][c+3], a1))));
    a2 = fmaf(w.x, q_lds[2][c], fmaf(w.y, q_lds[2][c+1],
         fmaf(w.z, q_lds[2][c+2], fmaf(w.w, q_lds[2][c+3], a2))));
    a3 = fmaf(w.x, q_lds[3][c], fmaf(w.y, q_lds[3][c+1],
         fmaf(w.z, q_lds[3][c+2], fmaf(w.w, q_lds[3][c+3], a3))));
  }
  float av[4] = {a0, a1, a2, a3};
  #pragma unroll
  for (int rl = 0; rl < 4; ++rl) {
    int r = r0 + rl;
    int l = r >> 3, nn = r & 7;
    int o = (((nn << 7) + l) << 8) + tid;
    _Float16 h = (_Float16)av[rl];
    q_hi[o] = h;
    q_lo[o] = (_Float16)(av[rl] - (float)h);
  }
}

// ---------------------------------------------------------------------------
// Main fused kernel: per block one n, 32 s-rows (32.5 KB LDS -> 4 blocks/CU).
//   stage (memory+pos) -> split-f16 in LDS (xor-swizzled 16B chunks)
//   GEMM1 (MFMA, 3-term split): k_proj 32x256, + bias, fp32 row norms
//   writeback normalized k into same LDS ([s][b], GEMM2 B-operand layout)
//   GEMM2 (MFMA, 3-term split): logits 128x32, fused argmax + u64 atomicMax
__global__ __launch_bounds__(256, 4) void k_main(
    const float* __restrict__ memory, const float* __restrict__ pos,
    const _Float16* __restrict__ Wp_hi, const _Float16* __restrict__ Wp_lo,
    const float* __restrict__ bp,
    const _Float16* __restrict__ q_hi, const _Float16* __restrict__ q_lo,
    unsigned long long* __restrict__ packed) {
  __shared__ __align__(16) unsigned short smu[2 * 32 * 256];  // 32 KB
  __shared__ float snorm[4][32];                              // 512 B
  unsigned short* a_hi = smu;            // [32][256] f16 bits (swizzled)
  unsigned short* a_lo = smu + 8192;

  int tid = threadIdx.x;
  int w = tid >> 6;                      // wave 0..3
  int lane = tid & 63;
  int l15 = lane & 15, quad = lane >> 4;
  int n = blockIdx.y;
  int s_base = blockIdx.x << 5;          // 32 s-rows per block

  // ---- stage A-tile: (memory+pos) -> f16 hi/lo, chunk-swizzled ----
  {
    int half = tid >> 5;                 // 0..7
    int chunk = tid & 31;                // 8-element chunk id
    int c0 = chunk << 3;
    #pragma unroll
    for (int it = 0; it < 4; ++it) {
      int srow = (it << 3) + half;
      int g = (((s_base + srow) << 3) + n) * 256 + c0;
      float4 m0 = *(const float4*)(memory + g);
      float4 m1 = *(const float4*)(memory + g + 4);
      float4 p0 = *(const float4*)(pos + g);
      float4 p1 = *(const float4*)(pos + g + 4);
      float f[8] = {m0.x + p0.x, m0.y + p0.y, m0.z + p0.z, m0.w + p0.w,
                    m1.x + p1.x, m1.y + p1.y, m1.z + p1.z, m1.w + p1.w};
      half8 hv, lv;
      #pragma unroll
      for (int j = 0; j < 8; ++j) {
        _Float16 h = (_Float16)f[j];
        hv[j] = h;
        lv[j] = (_Float16)(f[j] - (float)h);
      }
      int p = chunk ^ (srow & 15);
      *(half8*)(a_hi + (srow << 8) + (p << 3)) = hv;
      *(half8*)(a_lo + (srow << 8) + (p << 3)) = lv;
    }
  }
  __syncthreads();

  // ---- GEMM1: D[s][b] = sum_c k[s][c] * Wp[b][c]  (3-term split f16) ----
  f32x4 acc1[2][4];   // [m: s-tile][bn: b-tile]; wave w owns b in [w*64,w*64+64)
  #pragma unroll
  for (int m = 0; m < 2; ++m)
    #pragma unroll
    for (int bn = 0; bn < 4; ++bn) acc1[m][bn] = (f32x4)(0.0f);

  for (int kk = 0; kk < 8; ++kk) {
    int cofs = (kk << 5) + (quad << 3);           // c base for this lane
    half8 ah[2], al[2];
    #pragma unroll
    for (int m = 0; m < 2; ++m) {
      int s = (m << 4) + l15;
      int p = (cofs >> 3) ^ l15;                  // chunk swizzle
      ah[m] = *(const half8*)(a_hi + (s << 8) + (p << 3));
      al[m] = *(const half8*)(a_lo + (s << 8) + (p << 3));
    }
    #pragma unroll
    for (int bn = 0; bn < 4; ++bn) {
      int b = (w << 6) + (bn << 4) + l15;
      half8 wh = *(const half8*)(Wp_hi + (b << 8) + cofs);
      half8 wl = *(const half8*)(Wp_lo + (b << 8) + cofs);
      #pragma unroll
      for (int m = 0; m < 2; ++m) {
        acc1[m][bn] = __builtin_amdgcn_mfma_f32_16x16x32_f16(ah[m], wh, acc1[m][bn], 0, 0, 0);
        acc1[m][bn] = __builtin_amdgcn_mfma_f32_16x16x32_f16(ah[m], wl, acc1[m][bn], 0, 0, 0);
        acc1[m][bn] = __builtin_amdgcn_mfma_f32_16x16x32_f16(al[m], wh, acc1[m][bn], 0, 0, 0);
      }
    }
  }

  // ---- bias + fp32 row L2-norms (C/D layout: col=l15, row=quad*4+r) ----
  float bpv[4];
  #pragma unroll
  for (int bn = 0; bn < 4; ++bn) bpv[bn] = bp[(w << 6) + (bn << 4) + l15];
  float n2[2][4];
  #pragma unroll
  for (int m = 0; m < 2; ++m)
    #pragma unroll
    for (int r = 0; r < 4; ++r) {
      float s = 0.f;
      #pragma unroll
      for (int bn = 0; bn < 4; ++bn) {
        float v = acc1[m][bn][r] + bpv[bn];
        acc1[m][bn][r] = v;
        s = fmaf(v, v, s);
      }
      n2[m][r] = s;
    }
  #pragma unroll
  for (int off = 1; off < 16; off <<= 1)
    #pragma unroll
    for (int m = 0; m < 2; ++m)
      #pragma unroll
      for (int r = 0; r < 4; ++r) n2[m][r] += __shfl_xor(n2[m][r], off, 64);

  // per-wave partial norms to separate buffer (no aliasing with a_hi/a_lo)
  if (l15 == 0) {
    #pragma unroll
    for (int m = 0; m < 2; ++m)
      #pragma unroll
      for (int r = 0; r < 4; ++r)
        snorm[w][(m << 4) + (quad << 2) + r] = n2[m][r];
  }
  __syncthreads();   // (A) GEMM1 LDS reads done + snorm visible
  float rn[2][4];
  #pragma unroll
  for (int m = 0; m < 2; ++m)
    #pragma unroll
    for (int r = 0; r < 4; ++r) {
      int s = (m << 4) + (quad << 2) + r;
      float t = snorm[0][s] + snorm[1][s] + snorm[2][s] + snorm[3][s];
      rn[m][r] = 1.f / fmaxf(sqrtf(t), 1e-12f);
    }

  // ---- writeback normalized k as GEMM2 B-operand: kn[s][b], swizzled ----
  unsigned short* kn_hi = smu;
  unsigned short* kn_lo = smu + 8192;
  #pragma unroll
  for (int m = 0; m < 2; ++m)
    #pragma unroll
    for (int bn = 0; bn < 4; ++bn)
      #pragma unroll
      for (int r = 0; r < 4; ++r) {
        int s = (m << 4) + (quad << 2) + r;
        int b = (w << 6) + (bn << 4) + l15;
        float v = acc1[m][bn][r] * rn[m][r];
        _Float16 h = (_Float16)v;
        _Float16 lo = (_Float16)(v - (float)h);
        int p = (b >> 3) ^ (s & 15);
        int off = (s << 8) + (p << 3) + (b & 7);
        *(_Float16*)(kn_hi + off) = h;
        *(_Float16*)(kn_lo + off) = lo;
      }
  __syncthreads();   // (B)

  // ---- GEMM2: logits[l][s] = sum_b q[l][b] * kn[s][b] (3-term split) ----
  f32x4 acc2[2][2];   // [m: l-tile][sn: s-tile]; wave w owns l in [w*32,w*32+32)
  #pragma unroll
  for (int m = 0; m < 2; ++m)
    #pragma unroll
    for (int sn = 0; sn < 2; ++sn) acc2[m][sn] = (f32x4)(0.0f);

  const _Float16* qhb = q_hi + (n << 15);
  const _Float16* qlb = q_lo + (n << 15);
  for (int kk = 0; kk < 8; ++kk) {
    int b0 = (kk << 5) + (quad << 3);
    half8 qh[2], ql[2];
    #pragma unroll
    for (int m = 0; m < 2; ++m) {
      int l = (w << 5) + (m << 4) + l15;
      qh[m] = *(const half8*)(qhb + (l << 8) + b0);
      ql[m] = *(const half8*)(qlb + (l << 8) + b0);
    }
    #pragma unroll
    for (int sn = 0; sn < 2; ++sn) {
      int s = (sn << 4) + l15;
      int p = (b0 >> 3) ^ l15;
      half8 kh = *(const half8*)(kn_hi + (s << 8) + (p << 3));
      half8 kl = *(const half8*)(kn_lo + (s << 8) + (p << 3));
      #pragma unroll
      for (int m = 0; m < 2; ++m) {
        acc2[m][sn] = __builtin_amdgcn_mfma_f32_16x16x32_f16(qh[m], kh, acc2[m][sn], 0, 0, 0);
        acc2[m][sn] = __builtin_amdgcn_mfma_f32_16x16x32_f16(qh[m], kl, acc2[m][sn], 0, 0, 0);
        acc2[m][sn] = __builtin_amdgcn_mfma_f32_16x16x32_f16(ql[m], kh, acc2[m][sn], 0, 0, 0);
      }
    }
  }

  // ---- fused argmax over this tile's 32 s (ties -> min s) ----
  float mv[8];
  int mi[8];
  #pragma unroll
  for (int m = 0; m < 2; ++m)
    #pragma unroll
    for (int r = 0; r < 4; ++r) {
      int i = (m << 2) + r;
      mv[i] = acc2[m][0][r];
      mi[i] = s_base + l15;
      float v = acc2[m][1][r];
      int si = s_base + 16 + l15;
      if (v > mv[i]) { mv[i] = v; mi[i] = si; }
    }
  #pragma unroll
  for (int off = 1; off < 16; off <<= 1)
    #pragma unroll
    for (int i = 0; i < 8; ++i) {
      float ov = __shfl_xor(mv[i], off, 64);
      int oi = __shfl_xor(mi[i], off, 64);
      if (ov > mv[i] || (ov == mv[i] && oi < mi[i])) { mv[i] = ov; mi[i] = oi; }
    }
  if (l15 == 0) {
    #pragma unroll
    for (int i = 0; i < 8; ++i) {
      int m = i >> 2, r = i & 3;
      int l = (w << 5) + (m << 4) + (quad << 2) + r;
      unsigned ub = __float_as_uint(mv[i]);
      ub = (ub & 0x80000000u) ? ~ub : (ub | 0x80000000u);
      unsigned long long pk = ((unsigned long long)ub << 32) |
                              (unsigned long long)(16383u - (unsigned)mi[i]);
      atomicMax(packed + (n << 7) + l, pk);
    }
  }
}

// ---------------------------------------------------------------------------
// Gather winners, recompute k_proj/v_proj (fp32) for the 1024 selected rows,
// output projection, residual, LayerNorm. 4 rows per block, 256 blocks.
__global__ __launch_bounds__(256) void k_final(
    const float* __restrict__ tgt,
    const float* __restrict__ memory, const float* __restrict__ pos,
    const float* __restrict__ WpT, const float* __restrict__ bp,
    const float* __restrict__ WvT, const float* __restrict__ bv,
    const float* __restrict__ WoT, const float* __restrict__ bo,
    const float* __restrict__ gamma, const float* __restrict__ beta,
    const unsigned long long* __restrict__ packed, float* __restrict__ out) {
  __shared__ __align__(16) float buf0[4][256];
  __shared__ __align__(16) float buf1[4][256];
  __shared__ __align__(16) float buf2[4][256];
  __shared__ float red[4][4][2];
  int tid = threadIdx.x;
  int r0 = blockIdx.x << 2;

  #pragma unroll
  for (int j = 0; j < 4; ++j) {
    int p = (j << 8) + tid;
    int rl = p >> 8, c = p & 255;
    int r = r0 + rl;
    int l = r >> 3, nn = r & 7;
    unsigned long long pk = packed[(nn << 7) + l];
    int sstar = (16383 - (int)(unsigned int)(pk & 0xffffffffu)) & 16383;
    int g = ((sstar << 3) + nn) * 256 + c;
    buf0[rl][c] = memory[g] + pos[g];
  }
  __syncthreads();

  float a[4];
  { float b0v = bp[tid];
    #pragma unroll
    for (int rl = 0; rl < 4; ++rl) a[rl] = b0v; }
  #pragma unroll 4
  for (int c = 0; c < 256; ++c) {
    float w = WpT[(c << 8) + tid];
    #pragma unroll
    for (int rl = 0; rl < 4; ++rl) a[rl] = fmaf(w, buf0[rl][c], a[rl]);
  }
  #pragma unroll
  for (int rl = 0; rl < 4; ++rl) buf1[rl][tid] = a[rl];
  __syncthreads();

  { float b0v = bv[tid];
    #pragma unroll
    for (int rl = 0; rl < 4; ++rl) a[rl] = b0v; }
  #pragma unroll 4
  for (int c = 0; c < 256; ++c) {
    float w = WvT[(c << 8) + tid];
    #pragma unroll
    for (int rl = 0; rl < 4; ++rl) a[rl] = fmaf(w, buf1[rl][c], a[rl]);
  }
  #pragma unroll
  for (int rl = 0; rl < 4; ++rl) buf2[rl][tid] = a[rl];
  __syncthreads();

  { float b0v = bo[tid];
    #pragma unroll
    for (int rl = 0; rl < 4; ++rl) a[rl] = b0v; }
  #pragma unroll 4
  for (int c = 0; c < 256; ++c) {
    float w = WoT[(c << 8) + tid];
    #pragma unroll
    for (int rl = 0; rl < 4; ++rl) a[rl] = fmaf(w, buf2[rl][c], a[rl]);
  }
  float x[4];
  #pragma unroll
  for (int rl = 0; rl < 4; ++rl)
    x[rl] = tgt[((r0 + rl) << 8) + tid] + a[rl];

  float s1[4], s2[4];
  #pragma unroll
  for (int rl = 0; rl < 4; ++rl) { s1[rl] = x[rl]; s2[rl] = x[rl] * x[rl]; }
  #pragma unroll
  for (int off = 1; off < 64; off <<= 1)
    #pragma unroll
    for (int rl = 0; rl < 4; ++rl) {
      s1[rl] += __shfl_xor(s1[rl], off, 64);
      s2[rl] += __shfl_xor(s2[rl], off, 64);
    }
  int wv = tid >> 6, ln = tid & 63;
  if (ln == 0) {
    #pragma unroll
    for (int rl = 0; rl < 4; ++rl) { red[wv][rl][0] = s1[rl]; red[wv][rl][1] = s2[rl]; }
  }
  __syncthreads();
  float g = gamma[tid], be = beta[tid];
  #pragma unroll
  for (int rl = 0; rl < 4; ++rl) {
    float S1 = red[0][rl][0] + red[1][rl][0] + red[2][rl][0] + red[3][rl][0];
    float S2 = red[0][rl][1] + red[1][rl][1] + red[2][rl][1] + red[3][rl][1];
    float mu = S1 * (1.f / 256.f);
    float var = S2 * (1.f / 256.f) - mu * mu;
    float rs = rsqrtf(var + 1e-5f);
    out[((r0 + rl) << 8) + tid] = (x[rl] - mu) * rs * g + be;
  }
}

// ---------------------------------------------------------------------------
extern "C" void kernel_launch(void* const* d_in, const int* in_sizes, int n_in,
                              void* d_out, int out_size, void* d_ws, size_t ws_size,
                              hipStream_t stream) {
  const float* tgt    = (const float*)d_in[0];
  const float* memory = (const float*)d_in[1];
  const float* pos    = (const float*)d_in[2];
  const float* qpos   = (const float*)d_in[3];
  const float* Wq     = (const float*)d_in[4];
  const float* bq     = (const float*)d_in[5];
  const float* Wp     = (const float*)d_in[6];
  const float* bp     = (const float*)d_in[7];
  const float* Wv     = (const float*)d_in[8];
  const float* bv     = (const float*)d_in[9];
  const float* Wo     = (const float*)d_in[10];
  const float* bo     = (const float*)d_in[11];
  const float* gamma  = (const float*)d_in[12];
  const float* beta   = (const float*)d_in[13];

  float* ws = (float*)d_ws;
  float* WpT = ws;                                   // [0, 65536)
  float* WvT = ws + 65536;                           // [65536, 131072)
  float* WoT = ws + 131072;                          // [131072, 196608)
  _Float16* Wp_hi = (_Float16*)(ws + 196608);        // 65536 halves
  _Float16* Wp_lo = (_Float16*)(ws + 229376);        // 65536 halves
  _Float16* q_hi  = (_Float16*)(ws + 262144);        // 262144 halves
  _Float16* q_lo  = (_Float16*)(ws + 393216);        // 262144 halves
  unsigned long long* packed = (unsigned long long*)(ws + 524288);  // 1024 u64
  float* out = (float*)d_out;

  k_prep_qproj<<<512, 256, 0, stream>>>(Wp, Wv, Wo, WpT, WvT, WoT,
                                        Wp_hi, Wp_lo, packed,
                                        tgt, qpos, Wq, bq, q_hi, q_lo);
  dim3 gb(S_P / 32, N_B);
  k_main<<<gb, 256, 0, stream>>>(memory, pos, Wp_hi, Wp_lo, bp, q_hi, q_lo, packed);
  k_final<<<256, 256, 0, stream>>>(tgt, memory, pos, WpT, bp, WvT, bv,
                                   WoT, bo, gamma, beta, packed, out);
}

// Round 5
// 509.052 us; speedup vs baseline: 1.1155x; 1.1155x over previous
//
#include <hip/hip_runtime.h>
#include <stdint.h>

// Problem constants: L=128, N=8, S=16384, C=B=V=256
#define L_Q 128
#define N_B 8
#define S_P 16384

typedef _Float16 half8 __attribute__((ext_vector_type(8)));
typedef float f32x4 __attribute__((ext_vector_type(4)));

// Workspace layout (float offsets) — total 526336 floats = 2,105,344 bytes:
//   WpT    fp32 [C][B]      65536 @ 0        (k_final, coalesced [c][b])
//   WvT    fp32 [B][V]      65536 @ 65536
//   WoT    fp32 [V][C]      65536 @ 131072
//   Wp_hi  f16  [B][C]      32768 @ 196608   (k_main GEMM1 B-operand)
//   Wp_lo  f16  [B][C]      32768 @ 229376
//   qw_hi  f16  [N][L][C]  131072 @ 262144   (k_main GEMM2' A-operand; qw=q_proj@Wp)
//   qw_lo  f16  [N][L][C]  131072 @ 393216
//   packed u64  [N*L]        2048 @ 524288

// ---------------------------------------------------------------------------
// Merged prep (blocks 0..255) + q_proj->qw (blocks 256..511).
__global__ __launch_bounds__(256) void k_prep_qproj(
    const float* __restrict__ Wp, const float* __restrict__ Wv,
    const float* __restrict__ Wo,
    float* __restrict__ WpT, float* __restrict__ WvT, float* __restrict__ WoT,
    _Float16* __restrict__ Wp_hi, _Float16* __restrict__ Wp_lo,
    unsigned long long* __restrict__ packed,
    const float* __restrict__ tgt, const float* __restrict__ qpos,
    const float* __restrict__ Wq, const float* __restrict__ bq,
    _Float16* __restrict__ qw_hi, _Float16* __restrict__ qw_lo) {
  __shared__ __align__(16) float q_lds[4][256];
  __shared__ __align__(16) float qp_lds[4][256];
  int tid = threadIdx.x;
  if (blockIdx.x < 256) {
    // ---- prep: fp32 transposes for k_final, f16 split of Wp for k_main ----
    int idx = (blockIdx.x << 8) + tid;     // 0..65535
    int r = idx >> 8, c = idx & 255;
    int t = (c << 8) + r;
    float wp = Wp[idx];
    WpT[t] = wp;
    WvT[t] = Wv[idx];
    WoT[t] = Wo[idx];
    _Float16 h = (_Float16)wp;
    Wp_hi[idx] = h;                        // [b][c], no transpose
    Wp_lo[idx] = (_Float16)(wp - (float)h);
    if (idx < N_B * L_Q) packed[idx] = 0ull;  // any real logit packs to > 0
    return;
  }
  // ---- q_proj (fp32 VALU) then qw = q_proj @ Wp (fp32), split to f16 ----
  int r0 = (blockIdx.x - 256) << 2;        // 4 rows (l*8+n)
  #pragma unroll
  for (int j = 0; j < 4; ++j) {
    int p = (j << 8) + tid;
    int rl = p >> 8, c = p & 255;
    int g = ((r0 + rl) << 8) + c;          // (l*8+n) row-major
    q_lds[rl][c] = tgt[g] + qpos[g];
  }
  __syncthreads();
  float bqv = bq[tid];
  float a0 = bqv, a1 = bqv, a2 = bqv, a3 = bqv;
  #pragma unroll 4
  for (int c = 0; c < 256; c += 4) {
    float4 w = *(const float4*)(Wq + (tid << 8) + c);   // row per thread
    a0 = fmaf(w.x, q_lds[0][c], fmaf(w.y, q_lds[0][c+1],
         fmaf(w.z, q_lds[0][c+2], fmaf(w.w, q_lds[0][c+3], a0))));
    a1 = fmaf(w.x, q_lds[1][c], fmaf(w.y, q_lds[1][c+1],
         fmaf(w.z, q_lds[1][c+2], fmaf(w.w, q_lds[1][c+3], a1))));
    a2 = fmaf(w.x, q_lds[2][c], fmaf(w.y, q_lds[2][c+1],
         fmaf(w.z, q_lds[2][c+2], fmaf(w.w, q_lds[2][c+3], a2))));
    a3 = fmaf(w.x, q_lds[3][c], fmaf(w.y, q_lds[3][c+1],
         fmaf(w.z, q_lds[3][c+2], fmaf(w.w, q_lds[3][c+3], a3))));
  }
  qp_lds[0][tid] = a0;  // q_proj rows (thread = b)
  qp_lds[1][tid] = a1;
  qp_lds[2][tid] = a2;
  qp_lds[3][tid] = a3;
  __syncthreads();
  // qw[row][c] = sum_b q_proj[row][b] * Wp[b][c]   (thread = c)
  float w0 = 0.f, w1 = 0.f, w2 = 0.f, w3 = 0.f;
  #pragma unroll 4
  for (int b = 0; b < 256; ++b) {
    float wp = Wp[(b << 8) + tid];         // coalesced across lanes
    float q0 = qp_lds[0][b], q1 = qp_lds[1][b];   // broadcast (free)
    float q2 = qp_lds[2][b], q3 = qp_lds[3][b];
    w0 = fmaf(q0, wp, w0);
    w1 = fmaf(q1, wp, w1);
    w2 = fmaf(q2, wp, w2);
    w3 = fmaf(q3, wp, w3);
  }
  float wv[4] = {w0, w1, w2, w3};
  #pragma unroll
  for (int rl = 0; rl < 4; ++rl) {
    int r = r0 + rl;
    int l = r >> 3, nn = r & 7;
    int o = (((nn << 7) + l) << 8) + tid;  // [n][l][c]
    _Float16 h = (_Float16)wv[rl];
    qw_hi[o] = h;
    qw_lo[o] = (_Float16)(wv[rl] - (float)h);
  }
}

// ---------------------------------------------------------------------------
// Main fused kernel: per block one n, 64 s-rows (65.5 KB LDS, 2 blocks/CU).
//   stage (memory+pos) -> split-f16 k-tile in LDS (xor-swizzled 16B chunks)
//   merged kk-loop: GEMM1 (norms: kp = k@WpT) + GEMM2' (raw logits = qw@k^T)
//     sharing the same LDS A/B fragments — no writeback, no mid-GEMM barrier
//   one barrier for the cross-wave norm exchange, then scale+argmax+atomicMax
__global__ __launch_bounds__(256, 2) void k_main(
    const float* __restrict__ memory, const float* __restrict__ pos,
    const _Float16* __restrict__ Wp_hi, const _Float16* __restrict__ Wp_lo,
    const float* __restrict__ bp,
    const _Float16* __restrict__ qw_hi, const _Float16* __restrict__ qw_lo,
    unsigned long long* __restrict__ packed) {
  __shared__ __align__(16) unsigned short smu[2 * 64 * 256];  // 64 KB
  __shared__ float snorm[4][64];                              // 1 KB
  unsigned short* a_hi = smu;            // k-tile [64][256] f16 bits, swizzled
  unsigned short* a_lo = smu + 16384;

  int tid = threadIdx.x;
  int w = tid >> 6;                      // wave 0..3
  int lane = tid & 63;
  int l15 = lane & 15, quad = lane >> 4;
  int n = blockIdx.y;
  int s_base = blockIdx.x << 6;          // 64 s-rows per block

  // ---- stage k-tile: (memory+pos) -> f16 hi/lo, chunk-swizzled ----
  {
    int half = tid >> 5;                 // 0..7
    int chunk = tid & 31;                // 8-element chunk id
    int c0 = chunk << 3;
    #pragma unroll
    for (int it = 0; it < 8; ++it) {
      int srow = (it << 3) + half;
      int g = (((s_base + srow) << 3) + n) * 256 + c0;
      float4 m0 = *(const float4*)(memory + g);
      float4 m1 = *(const float4*)(memory + g + 4);
      float4 p0 = *(const float4*)(pos + g);
      float4 p1 = *(const float4*)(pos + g + 4);
      float f[8] = {m0.x + p0.x, m0.y + p0.y, m0.z + p0.z, m0.w + p0.w,
                    m1.x + p1.x, m1.y + p1.y, m1.z + p1.z, m1.w + p1.w};
      half8 hv, lv;
      #pragma unroll
      for (int j = 0; j < 8; ++j) {
        _Float16 h = (_Float16)f[j];
        hv[j] = h;
        lv[j] = (_Float16)(f[j] - (float)h);
      }
      int p = chunk ^ (srow & 15);
      *(half8*)(a_hi + (srow << 8) + (p << 3)) = hv;
      *(half8*)(a_lo + (srow << 8) + (p << 3)) = lv;
    }
  }
  __syncthreads();

  // ---- merged GEMM1 + GEMM2' over the c (k) dimension ----
  // GEMM1: kp[s][b] = sum_c k[s][c]*Wp[b][c]; wave w owns b in [w*64, w*64+64)
  // GEMM2': raw[l][s] = sum_c qw[l][c]*k[s][c]; wave w owns l in [w*32, w*32+32)
  // k-tile fragments (A for GEMM1, B for GEMM2') are identical — load once.
  f32x4 acc1[4][4];
  f32x4 acc2[2][4];
  #pragma unroll
  for (int m = 0; m < 4; ++m)
    #pragma unroll
    for (int bn = 0; bn < 4; ++bn) acc1[m][bn] = (f32x4)(0.0f);
  #pragma unroll
  for (int m = 0; m < 2; ++m)
    #pragma unroll
    for (int sn = 0; sn < 4; ++sn) acc2[m][sn] = (f32x4)(0.0f);

  const _Float16* qhb = qw_hi + (n << 15);
  const _Float16* qlb = qw_lo + (n << 15);

  for (int kk = 0; kk < 8; ++kk) {
    int cofs = (kk << 5) + (quad << 3);           // c base for this lane
    half8 ah[4], al[4];
    #pragma unroll
    for (int m = 0; m < 4; ++m) {
      int s = (m << 4) + l15;
      int p = (cofs >> 3) ^ l15;                  // chunk swizzle
      ah[m] = *(const half8*)(a_hi + (s << 8) + (p << 3));
      al[m] = *(const half8*)(a_lo + (s << 8) + (p << 3));
    }
    // GEMM1 (3-term split: hh + hl + lh)
    #pragma unroll
    for (int bn = 0; bn < 4; ++bn) {
      int b = (w << 6) + (bn << 4) + l15;
      half8 wh = *(const half8*)(Wp_hi + (b << 8) + cofs);
      half8 wl = *(const half8*)(Wp_lo + (b << 8) + cofs);
      #pragma unroll
      for (int m = 0; m < 4; ++m) {
        acc1[m][bn] = __builtin_amdgcn_mfma_f32_16x16x32_f16(ah[m], wh, acc1[m][bn], 0, 0, 0);
        acc1[m][bn] = __builtin_amdgcn_mfma_f32_16x16x32_f16(ah[m], wl, acc1[m][bn], 0, 0, 0);
        acc1[m][bn] = __builtin_amdgcn_mfma_f32_16x16x32_f16(al[m], wh, acc1[m][bn], 0, 0, 0);
      }
    }
    // GEMM2' (3-term split), B-fragments = ah/al
    half8 qh[2], ql[2];
    #pragma unroll
    for (int m = 0; m < 2; ++m) {
      int l = (w << 5) + (m << 4) + l15;
      qh[m] = *(const half8*)(qhb + (l << 8) + cofs);
      ql[m] = *(const half8*)(qlb + (l << 8) + cofs);
    }
    #pragma unroll
    for (int sn = 0; sn < 4; ++sn) {
      #pragma unroll
      for (int m = 0; m < 2; ++m) {
        acc2[m][sn] = __builtin_amdgcn_mfma_f32_16x16x32_f16(qh[m], ah[sn], acc2[m][sn], 0, 0, 0);
        acc2[m][sn] = __builtin_amdgcn_mfma_f32_16x16x32_f16(qh[m], al[sn], acc2[m][sn], 0, 0, 0);
        acc2[m][sn] = __builtin_amdgcn_mfma_f32_16x16x32_f16(ql[m], ah[sn], acc2[m][sn], 0, 0, 0);
      }
    }
  }

  // ---- bias + fp32 row L2-norms (C/D layout: col b=l15, row s=quad*4+r) ----
  float bpv[4];
  #pragma unroll
  for (int bn = 0; bn < 4; ++bn) bpv[bn] = bp[(w << 6) + (bn << 4) + l15];
  float n2[4][4];
  #pragma unroll
  for (int m = 0; m < 4; ++m)
    #pragma unroll
    for (int r = 0; r < 4; ++r) {
      float s = 0.f;
      #pragma unroll
      for (int bn = 0; bn < 4; ++bn) {
        float v = acc1[m][bn][r] + bpv[bn];
        s = fmaf(v, v, s);
      }
      n2[m][r] = s;
    }
  #pragma unroll
  for (int off = 1; off < 16; off <<= 1)
    #pragma unroll
    for (int m = 0; m < 4; ++m)
      #pragma unroll
      for (int r = 0; r < 4; ++r) n2[m][r] += __shfl_xor(n2[m][r], off, 64);
  if (l15 == 0) {
    #pragma unroll
    for (int m = 0; m < 4; ++m)
      #pragma unroll
      for (int r = 0; r < 4; ++r)
        snorm[w][(m << 4) + (quad << 2) + r] = n2[m][r];
  }
  __syncthreads();   // the only mid-kernel barrier: norm exchange

  float rn4[4];
  #pragma unroll
  for (int sn = 0; sn < 4; ++sn) {
    int s = (sn << 4) + l15;
    float t = snorm[0][s] + snorm[1][s] + snorm[2][s] + snorm[3][s];
    rn4[sn] = 1.f / fmaxf(sqrtf(t), 1e-12f);
  }

  // ---- scale + fused argmax over this tile's 64 s (ties -> min s) ----
  // acc2[m][sn][r]: l = w*32+m*16+quad*4+r, s = sn*16+l15
  float mv[8];
  int mi[8];
  #pragma unroll
  for (int m = 0; m < 2; ++m)
    #pragma unroll
    for (int r = 0; r < 4; ++r) {
      int i = (m << 2) + r;
      mv[i] = acc2[m][0][r] * rn4[0];
      mi[i] = s_base + l15;
      #pragma unroll
      for (int sn = 1; sn < 4; ++sn) {
        float v = acc2[m][sn][r] * rn4[sn];
        int si = s_base + (sn << 4) + l15;
        if (v > mv[i]) { mv[i] = v; mi[i] = si; }
      }
    }
  #pragma unroll
  for (int off = 1; off < 16; off <<= 1)
    #pragma unroll
    for (int i = 0; i < 8; ++i) {
      float ov = __shfl_xor(mv[i], off, 64);
      int oi = __shfl_xor(mi[i], off, 64);
      if (ov > mv[i] || (ov == mv[i] && oi < mi[i])) { mv[i] = ov; mi[i] = oi; }
    }
  if (l15 == 0) {
    #pragma unroll
    for (int i = 0; i < 8; ++i) {
      int m = i >> 2, r = i & 3;
      int l = (w << 5) + (m << 4) + (quad << 2) + r;
      unsigned ub = __float_as_uint(mv[i]);
      ub = (ub & 0x80000000u) ? ~ub : (ub | 0x80000000u);
      unsigned long long pk = ((unsigned long long)ub << 32) |
                              (unsigned long long)(16383u - (unsigned)mi[i]);
      atomicMax(packed + (n << 7) + l, pk);
    }
  }
}

// ---------------------------------------------------------------------------
// Gather winners, recompute k_proj/v_proj (fp32) for the 1024 selected rows,
// output projection, residual, LayerNorm. 4 rows per block, 256 blocks.
__global__ __launch_bounds__(256) void k_final(
    const float* __restrict__ tgt,
    const float* __restrict__ memory, const float* __restrict__ pos,
    const float* __restrict__ WpT, const float* __restrict__ bp,
    const float* __restrict__ WvT, const float* __restrict__ bv,
    const float* __restrict__ WoT, const float* __restrict__ bo,
    const float* __restrict__ gamma, const float* __restrict__ beta,
    const unsigned long long* __restrict__ packed, float* __restrict__ out) {
  __shared__ __align__(16) float buf0[4][256];
  __shared__ __align__(16) float buf1[4][256];
  __shared__ __align__(16) float buf2[4][256];
  __shared__ float red[4][4][2];
  int tid = threadIdx.x;
  int r0 = blockIdx.x << 2;

  #pragma unroll
  for (int j = 0; j < 4; ++j) {
    int p = (j << 8) + tid;
    int rl = p >> 8, c = p & 255;
    int r = r0 + rl;
    int l = r >> 3, nn = r & 7;
    unsigned long long pk = packed[(nn << 7) + l];
    int sstar = (16383 - (int)(unsigned int)(pk & 0xffffffffu)) & 16383;
    int g = ((sstar << 3) + nn) * 256 + c;
    buf0[rl][c] = memory[g] + pos[g];
  }
  __syncthreads();

  float a[4];
  { float b0v = bp[tid];
    #pragma unroll
    for (int rl = 0; rl < 4; ++rl) a[rl] = b0v; }
  #pragma unroll 4
  for (int c = 0; c < 256; ++c) {
    float w = WpT[(c << 8) + tid];
    #pragma unroll
    for (int rl = 0; rl < 4; ++rl) a[rl] = fmaf(w, buf0[rl][c], a[rl]);
  }
  #pragma unroll
  for (int rl = 0; rl < 4; ++rl) buf1[rl][tid] = a[rl];
  __syncthreads();

  { float b0v = bv[tid];
    #pragma unroll
    for (int rl = 0; rl < 4; ++rl) a[rl] = b0v; }
  #pragma unroll 4
  for (int c = 0; c < 256; ++c) {
    float w = WvT[(c << 8) + tid];
    #pragma unroll
    for (int rl = 0; rl < 4; ++rl) a[rl] = fmaf(w, buf1[rl][c], a[rl]);
  }
  #pragma unroll
  for (int rl = 0; rl < 4; ++rl) buf2[rl][tid] = a[rl];
  __syncthreads();

  { float b0v = bo[tid];
    #pragma unroll
    for (int rl = 0; rl < 4; ++rl) a[rl] = b0v; }
  #pragma unroll 4
  for (int c = 0; c < 256; ++c) {
    float w = WoT[(c << 8) + tid];
    #pragma unroll
    for (int rl = 0; rl < 4; ++rl) a[rl] = fmaf(w, buf2[rl][c], a[rl]);
  }
  float x[4];
  #pragma unroll
  for (int rl = 0; rl < 4; ++rl)
    x[rl] = tgt[((r0 + rl) << 8) + tid] + a[rl];

  float s1[4], s2[4];
  #pragma unroll
  for (int rl = 0; rl < 4; ++rl) { s1[rl] = x[rl]; s2[rl] = x[rl] * x[rl]; }
  #pragma unroll
  for (int off = 1; off < 64; off <<= 1)
    #pragma unroll
    for (int rl = 0; rl < 4; ++rl) {
      s1[rl] += __shfl_xor(s1[rl], off, 64);
      s2[rl] += __shfl_xor(s2[rl], off, 64);
    }
  int wv = tid >> 6, ln = tid & 63;
  if (ln == 0) {
    #pragma unroll
    for (int rl = 0; rl < 4; ++rl) { red[wv][rl][0] = s1[rl]; red[wv][rl][1] = s2[rl]; }
  }
  __syncthreads();
  float g = gamma[tid], be = beta[tid];
  #pragma unroll
  for (int rl = 0; rl < 4; ++rl) {
    float S1 = red[0][rl][0] + red[1][rl][0] + red[2][rl][0] + red[3][rl][0];
    float S2 = red[0][rl][1] + red[1][rl][1] + red[2][rl][1] + red[3][rl][1];
    float mu = S1 * (1.f / 256.f);
    float var = S2 * (1.f / 256.f) - mu * mu;
    float rs = rsqrtf(var + 1e-5f);
    out[((r0 + rl) << 8) + tid] = (x[rl] - mu) * rs * g + be;
  }
}

// ---------------------------------------------------------------------------
extern "C" void kernel_launch(void* const* d_in, const int* in_sizes, int n_in,
                              void* d_out, int out_size, void* d_ws, size_t ws_size,
                              hipStream_t stream) {
  const float* tgt    = (const float*)d_in[0];
  const float* memory = (const float*)d_in[1];
  const float* pos    = (const float*)d_in[2];
  const float* qpos   = (const float*)d_in[3];
  const float* Wq     = (const float*)d_in[4];
  const float* bq     = (const float*)d_in[5];
  const float* Wp     = (const float*)d_in[6];
  const float* bp     = (const float*)d_in[7];
  const float* Wv     = (const float*)d_in[8];
  const float* bv     = (const float*)d_in[9];
  const float* Wo     = (const float*)d_in[10];
  const float* bo     = (const float*)d_in[11];
  const float* gamma  = (const float*)d_in[12];
  const float* beta   = (const float*)d_in[13];

  float* ws = (float*)d_ws;
  float* WpT = ws;                                   // [0, 65536)
  float* WvT = ws + 65536;                           // [65536, 131072)
  float* WoT = ws + 131072;                          // [131072, 196608)
  _Float16* Wp_hi = (_Float16*)(ws + 196608);        // 65536 halves
  _Float16* Wp_lo = (_Float16*)(ws + 229376);        // 65536 halves
  _Float16* qw_hi = (_Float16*)(ws + 262144);        // 262144 halves
  _Float16* qw_lo = (_Float16*)(ws + 393216);        // 262144 halves
  unsigned long long* packed = (unsigned long long*)(ws + 524288);  // 1024 u64
  float* out = (float*)d_out;

  k_prep_qproj<<<512, 256, 0, stream>>>(Wp, Wv, Wo, WpT, WvT, WoT,
                                        Wp_hi, Wp_lo, packed,
                                        tgt, qpos, Wq, bq, qw_hi, qw_lo);
  dim3 gb(S_P / 64, N_B);
  k_main<<<gb, 256, 0, stream>>>(memory, pos, Wp_hi, Wp_lo, bp,
                                 qw_hi, qw_lo, packed);
  k_final<<<256, 256, 0, stream>>>(tgt, memory, pos, WpT, bp, WvT, bv,
                                   WoT, bo, gamma, beta, packed, out);
}